// Round 17
// baseline (204.402 us; speedup 1.0000x reference)
//
#include <hip/hip_runtime.h>
#include <math.h>

#define NN 100000
#define EE 600000
#define RR 2
#define DD 128
#define HH 8
#define DHH 16
#define RN (RR * NN)
#define NT 26     // N-tiles: 8 (s0) + 8 (s1) + 8 (res) + 1 (sc_dst) + 1 (sc_src)
#define MTOT 6250 // total m-tiles (16 nodes each)
#define NB3 ((MTOT + 3) / 4)                  // node3 blocks (4 waves each)
#define CHUNK 4096
#define NCH ((EE + CHUNK - 1) / CHUNK)        // 147 chunks per relation
#define BINW 512
#define NBIN ((NN + BINW - 1) / BINW)         // 196 bins per relation
#define BCAPD 4096                            // LDS key capacity in binfin

typedef unsigned short ushort_t;
typedef short bf16x8 __attribute__((ext_vector_type(8)));
typedef float f32x4 __attribute__((ext_vector_type(4)));
typedef unsigned short u16x4 __attribute__((ext_vector_type(4)));

__device__ __forceinline__ float lrelu(float v) { return v >= 0.f ? v : 0.2f * v; }

// f32 -> bf16 (round to nearest even), bf16 -> f32 (exact)
__device__ __forceinline__ ushort_t f2bf(float f) {
    unsigned int u = __float_as_uint(f);
    u = (u + 0x7FFFu + ((u >> 16) & 1u)) >> 16;
    return (ushort_t)u;
}
__device__ __forceinline__ float bf2f(ushort_t u) {
    return __uint_as_float(((unsigned int)u) << 16);
}

// ---- K1: compose1 (Wpn, Wres_c, bias folds) + fused prep + trailing binct ----
// binct also atomically accumulates per-bin TOTALS into bintot (for binstart).
__global__ __launch_bounds__(128) void k_compose1(
    const float* __restrict__ Wp, const float* __restrict__ bp,
    const float* __restrict__ Wn, const float* __restrict__ bn,
    const float* __restrict__ resW, const float* __restrict__ resb,
    const float* __restrict__ rel_emb, const float* __restrict__ Wrel,
    const float* __restrict__ Wprop, const float* __restrict__ bprop,
    const int* __restrict__ dst, int* __restrict__ binct, int* __restrict__ bintot,
    float* __restrict__ Wpn, float* __restrict__ bpn,
    float* __restrict__ Wres_c, float* __restrict__ bres_c,
    float* __restrict__ avec, float* __restrict__ rel_out) {
    const int tid = threadIdx.x;
    if (blockIdx.x >= DD) {
        // ---- binct role: per-chunk coarse-bin histogram + global bin totals ----
        __shared__ int bins[NBIN];
        const int b = blockIdx.x - DD;
        const int rel = b / NCH, blk = b - rel * NCH;
        for (int i = tid; i < NBIN; i += 128) bins[i] = 0;
        __syncthreads();
        for (int i = tid; i < CHUNK; i += 128) {
            int e = blk * CHUNK + i;
            if (e < EE)
                atomicAdd(&bins[__builtin_nontemporal_load(dst + rel * EE + e) >> 9], 1);
        }
        __syncthreads();
        for (int i = tid; i < NBIN; i += 128) {
            int v = bins[i];
            binct[((rel * NCH) + blk) * NBIN + i] = v;
            if (v) atomicAdd(&bintot[rel * NBIN + i], v);
        }
        return;
    }
    __shared__ float row[DD];
    const int rrow = blockIdx.x;
    row[tid] = Wp[rrow * DD + tid];
    __syncthreads();
    float acc1 = 0.f, acc2 = 0.f;
    for (int k = 0; k < DD; ++k) {
        float wv = row[k];
        acc1 = fmaf(wv, Wn[k * DD + tid], acc1);
        acc2 = fmaf(wv, resW[k * DD + tid], acc2);
    }
    Wpn[rrow * DD + tid] = acc1;
    Wres_c[rrow * DD + tid] = acc2;
    if (rrow == 0) {
        float b1 = 0.f, b2 = 0.f;
        for (int k = 0; k < DD; ++k) {
            b1 = fmaf(bp[k], Wn[k * DD + tid], b1);
            b2 = fmaf(bp[k], resW[k * DD + tid], b2);
        }
        bpn[tid] = b1 + bn[tid];
        bres_c[tid] = b2 + resb[tid];
    }
    // fused prep
    if (rrow < 4) {
        int idx = rrow * DD + tid;          // [0,512): avec
        int r = idx >> 8, o = idx & 255;
        float acc = 0.f;
        for (int i = 0; i < 64; ++i)
            acc += rel_emb[r * 64 + i] * Wrel[(r * 64 + i) * 256 + o];
        avec[idx] = acc;
    } else if (rrow < 6) {
        int o = (rrow - 4) * DD + tid;      // [0,256): rel_out
        int r = o >> 7, oo = o & 127;
        float acc = bprop[o];
        for (int i = 0; i < 64; ++i)
            acc += rel_emb[r * 64 + i] * Wprop[(r * 64 + i) * 128 + oo];
        rel_out[o] = acc;
    }
}

// ---- K2: compose2 (Ws_c, VdstT, biases) + PARALLEL runoff scans + binstart ----
__global__ __launch_bounds__(128) void k_compose2(
    const float* __restrict__ Wpn, const float* __restrict__ bpn,
    const float* __restrict__ Wsrc, const float* __restrict__ bsrc,
    const float* __restrict__ avec,
    const int* __restrict__ binct, const int* __restrict__ bintot,
    int* __restrict__ runoff, int* __restrict__ binstart,
    int* __restrict__ row_ptr,
    float* __restrict__ Ws_c, float* __restrict__ bs_c,
    float* __restrict__ VdstT, float* __restrict__ cdst) {
    const int tid = threadIdx.x;
    if (blockIdx.y >= DD) {
        __shared__ int part[128];
        const int sidx = (blockIdx.y - DD) * RR + blockIdx.x;
        if (sidx < RR * NBIN) {
            // ---- runoff: exclusive scan of this pair's 147 chunk counts ----
            const int rel = sidx / NBIN, bin = sidx - rel * NBIN;
            int v0 = 0, v1 = 0;
            const int c0 = 2 * tid, c1 = 2 * tid + 1;
            if (c0 < NCH) v0 = binct[((rel * NCH) + c0) * NBIN + bin];
            if (c1 < NCH) v1 = binct[((rel * NCH) + c1) * NBIN + bin];
            part[tid] = v0 + v1;
            __syncthreads();
            for (int off = 1; off < 128; off <<= 1) {
                int v = (tid >= off) ? part[tid - off] : 0;
                __syncthreads();
                part[tid] += v;
                __syncthreads();
            }
            int excl = (tid == 0) ? 0 : part[tid - 1];
            if (c0 < NCH) runoff[((rel * NCH) + c0) * NBIN + bin] = excl;
            if (c1 < NCH) runoff[((rel * NCH) + c1) * NBIN + bin] = excl + v0;
        }
        if (sidx == 512) {
            // ---- exclusive scan of bintot[512] -> binstart ----
            int s[4];
            #pragma unroll
            for (int q = 0; q < 4; ++q) s[q] = bintot[4 * tid + q];
            part[tid] = s[0] + s[1] + s[2] + s[3];
            __syncthreads();
            for (int off = 1; off < 128; off <<= 1) {
                int v = (tid >= off) ? part[tid - off] : 0;
                __syncthreads();
                part[tid] += v;
                __syncthreads();
            }
            int excl = (tid == 0) ? 0 : part[tid - 1];
            binstart[4 * tid]     = excl;
            binstart[4 * tid + 1] = excl + s[0];
            binstart[4 * tid + 2] = excl + s[0] + s[1];
            binstart[4 * tid + 3] = excl + s[0] + s[1] + s[2];
            if (tid == 0) row_ptr[RN] = RR * EE;
        }
        return;
    }
    __shared__ float row[DD];
    const int rel = blockIdx.x, rrow = blockIdx.y;
    row[tid] = Wpn[rrow * DD + tid];
    __syncthreads();
    const float* W = Wsrc + (size_t)rel * DD * DD;
    float acc = 0.f;
    for (int k = 0; k < DD; ++k) acc = fmaf(row[k], W[k * DD + tid], acc);
    Ws_c[(size_t)rel * DD * DD + rrow * DD + tid] = acc;
    if (tid < HH) {  // head = tid
        float v = 0.f;
        for (int d = 0; d < 16; ++d)
            v += row[tid * 16 + d] * avec[rel * 256 + tid * 32 + 16 + d];
        VdstT[(rel * HH + tid) * DD + rrow] = v;
    }
    if (rrow == 0) {
        float b = 0.f;
        for (int k = 0; k < DD; ++k) b = fmaf(bpn[k], W[k * DD + tid], b);
        bs_c[rel * DD + tid] = b + bsrc[rel * DD + tid];
        if (rel == 0 && tid < 16) {
            int r2 = tid >> 3, h2 = tid & 7;
            float c2 = 0.f;
            for (int d = 0; d < 16; ++d)
                c2 += bpn[h2 * 16 + d] * avec[r2 * 256 + h2 * 32 + 16 + d];
            cdst[tid] = c2;
        }
    }
}

// ---- K3: pack (MFMA B-fragments) + trailing binfill ----
__global__ __launch_bounds__(256) void k_pack(
    const float* __restrict__ Ws_c, const float* __restrict__ Wres_c,
    const float* __restrict__ VdstT, const float* __restrict__ avec,
    const float* __restrict__ bs_c,
    const int* __restrict__ src, const int* __restrict__ dst,
    const int* __restrict__ runoff, const int* __restrict__ binstart,
    int* __restrict__ ebuf,
    short* __restrict__ Wpk, float* __restrict__ csrc) {
    const int tid = threadIdx.x;
    if (blockIdx.x >= NT) {
        // ---- binfill role ----
        __shared__ int ofs[NBIN];
        __shared__ int bins[NBIN];
        const int b = blockIdx.x - NT;
        const int rel = b / NCH, blk = b - rel * NCH;
        if (tid < NBIN) {
            ofs[tid] = binstart[rel * NBIN + tid] +
                       runoff[((rel * NCH) + blk) * NBIN + tid];
            bins[tid] = 0;
        }
        __syncthreads();
        for (int i = tid; i < CHUNK; i += 256) {
            int e = blk * CHUNK + i;
            if (e < EE) {
                int d = __builtin_nontemporal_load(dst + rel * EE + e);
                int bb = d >> 9;
                int loc = atomicAdd(&bins[bb], 1);
                ebuf[ofs[bb] + loc] =
                    ((d & 511) << 17) | __builtin_nontemporal_load(src + rel * EE + e);
            }
        }
        return;
    }
    const int t = blockIdx.x;
    const int kt = tid >> 6;
    const int l = tid & 63;
    const int c16 = l & 15;
    bf16x8 v;
    #pragma unroll
    for (int j = 0; j < 8; ++j) {
        int k = kt * 32 + (l >> 4) * 8 + j;
        float f;
        if (t < 24) {
            int m = t >> 3;                    // 0=Ws0, 1=Ws1, 2=Wres
            int col = (t & 7) * 16 + c16;
            const float* W = (m == 0) ? Ws_c : (m == 1) ? Ws_c + DD * DD : Wres_c;
            f = W[k * DD + col];
        } else if (t == 24) {
            f = VdstT[c16 * DD + k];
        } else {
            int rel = c16 >> 3, h = c16 & 7;
            f = 0.f;
            for (int d = 0; d < 16; ++d)
                f += Ws_c[(size_t)rel * DD * DD + k * DD + h * 16 + d]
                     * avec[rel * 256 + h * 32 + d];
        }
        v[j] = (short)f2bf(f);
    }
    *(bf16x8*)(Wpk + ((size_t)(t * 4 + kt) * 64 + l) * 8) = v;
    if (t == 25 && tid < 16) {
        int rel = tid >> 3, h = tid & 7;
        float c = 0.f;
        for (int d = 0; d < 16; ++d)
            c += bs_c[rel * DD + h * 16 + d] * avec[rel * 256 + h * 32 + d];
        csrc[tid] = c;
    }
}

// ---- K4: node GEMM via MFMA + trailing binfin ----
__global__ __launch_bounds__(256) void k_node3(
    const float* __restrict__ x, const short* __restrict__ Wpk,
    const float* __restrict__ bs_c, const float* __restrict__ bres_c,
    const float* __restrict__ cdst, const float* __restrict__ csrc,
    const int* __restrict__ ebuf, const int* __restrict__ binstart,
    int* __restrict__ row_ptr, int* __restrict__ esrc,
    ushort_t* __restrict__ s_out, ushort_t* __restrict__ res_out,
    float* __restrict__ sc_src, float* __restrict__ sc_dst) {
    const int tid = threadIdx.x;
    if (blockIdx.x >= NB3) {
        // ---- binfin role: per-node counts + LDS scan -> row_ptr + esrc ----
        __shared__ int keys[BCAPD];
        __shared__ int cnt[BINW];
        __shared__ int scn[BINW];
        __shared__ int part[256];
        const int b = blockIdx.x - NB3;
        const int rel = b / NBIN, bin = b - rel * NBIN;
        const int p0 = binstart[rel * NBIN + bin];
        const int p1 = binstart[rel * NBIN + bin + 1];
        const int cntE = p1 - p0;
        const bool inlds = (cntE <= BCAPD);
        const int n0 = bin * BINW;
        const int nw = min(BINW, NN - n0);

        cnt[2 * tid] = 0; cnt[2 * tid + 1] = 0;
        __syncthreads();
        for (int i = tid; i < cntE; i += 256) {
            int k = __builtin_nontemporal_load(ebuf + p0 + i);
            if (inlds) keys[i] = k;
            atomicAdd(&cnt[k >> 17], 1);
        }
        __syncthreads();
        int a = cnt[2 * tid], c = cnt[2 * tid + 1];
        part[tid] = a + c;
        __syncthreads();
        for (int off = 1; off < 256; off <<= 1) {
            int v = (tid >= off) ? part[tid - off] : 0;
            __syncthreads();
            part[tid] += v;
            __syncthreads();
        }
        int excl = (tid == 0) ? 0 : part[tid - 1];
        scn[2 * tid] = excl;
        scn[2 * tid + 1] = excl + a;
        cnt[2 * tid] = 0; cnt[2 * tid + 1] = 0;   // reuse as placement cursors
        __syncthreads();
        for (int n = tid; n < nw; n += 256)
            row_ptr[rel * NN + n0 + n] = p0 + scn[n];
        for (int i = tid; i < cntE; i += 256) {
            int k = inlds ? keys[i] : ebuf[p0 + i];
            int low = k >> 17;
            int slot = atomicAdd(&cnt[low], 1);
            esrc[p0 + scn[low] + slot] = k & 0x1FFFF;
        }
        return;
    }
    const int l = tid & 63;
    const int w = tid >> 6;
    const int m16 = l & 15, g4 = l >> 4;
    const int mt = blockIdx.x * 4 + w;
    const bool live = (mt < MTOT);
    const int nb = (live ? mt : MTOT - 1) * 16;

    bf16x8 af[4];
    const float* xrow = x + (size_t)(nb + m16) * DD + g4 * 8;
    #pragma unroll
    for (int kt = 0; kt < 4; ++kt) {
        float4 v0 = *(const float4*)(xrow + kt * 32);
        float4 v1 = *(const float4*)(xrow + kt * 32 + 4);
        af[kt][0] = (short)f2bf(v0.x); af[kt][1] = (short)f2bf(v0.y);
        af[kt][2] = (short)f2bf(v0.z); af[kt][3] = (short)f2bf(v0.w);
        af[kt][4] = (short)f2bf(v1.x); af[kt][5] = (short)f2bf(v1.y);
        af[kt][6] = (short)f2bf(v1.z); af[kt][7] = (short)f2bf(v1.w);
    }

    for (int t = 0; t < NT; ++t) {
        f32x4 acc = {0.f, 0.f, 0.f, 0.f};
        #pragma unroll
        for (int kt = 0; kt < 4; ++kt) {
            bf16x8 b = *(const bf16x8*)(Wpk + ((size_t)(t * 4 + kt) * 64 + l) * 8);
            acc = __builtin_amdgcn_mfma_f32_16x16x32_bf16(af[kt], b, acc, 0, 0, 0);
        }
        if (!live) continue;
        if (t < 16) {
            const int rel = t >> 3, head = t & 7;
            const float bb = bs_c[rel * DD + head * 16 + m16];
            #pragma unroll
            for (int r = 0; r < 4; ++r) {
                const int node = nb + g4 * 4 + r;
                s_out[((size_t)rel * NN + node) * DD + head * 16 + m16] =
                    f2bf(acc[r] + bb);
            }
        } else if (t < 24) {
            const int col = (t - 16) * 16 + m16;
            const float bb = bres_c[col];
            #pragma unroll
            for (int r = 0; r < 4; ++r) {
                const int node = nb + g4 * 4 + r;
                res_out[(size_t)node * DD + col] = f2bf(acc[r] + bb);
            }
        } else if (t == 24) {
            const int rel = m16 >> 3, head = m16 & 7;
            const float bb = cdst[m16];
            #pragma unroll
            for (int r = 0; r < 4; ++r) {
                const int node = nb + g4 * 4 + r;
                sc_dst[((size_t)rel * NN + node) * HH + head] = acc[r] + bb;
            }
        } else {
            const int rel = m16 >> 3, head = m16 & 7;
            const float bb = csrc[m16];
            #pragma unroll
            for (int r = 0; r < 4; ++r) {
                const int node = nb + g4 * 4 + r;
                sc_src[((size_t)rel * NN + node) * HH + head] = acc[r] + bb;
            }
        }
    }
}

// ---- K5: fused gather: dedup-exp softmax + agg + gate + cross ----
// 4 edges per iteration: lane (h*4+q) computes score/exp for edge p+q at
// head h (each exp computed ONCE); quad shuffles broadcast (sr, e) for the
// payload FMAs. den via quad reduction.
__global__ __launch_bounds__(256) void k_gather_cross(
    const int* __restrict__ esrc, const int* __restrict__ row_ptr,
    const float* __restrict__ sc_src, const float* __restrict__ sc_dst,
    const ushort_t* __restrict__ s, const ushort_t* __restrict__ res_buf,
    const float* __restrict__ res_alpha, const float* __restrict__ crossW,
    float* __restrict__ out) {
    int n = blockIdx.x * 4 + (threadIdx.x >> 6);
    if (n >= NN) return;
    const int lane = threadIdx.x & 63;
    const int g = lane >> 5;
    const int j = lane & 31;
    const int h = j >> 2;
    const int q = j & 3;

    const int seg = g * NN + n;
    const int p0 = row_ptr[seg], p1 = row_ptr[seg + 1];
    const float sd = sc_dst[(size_t)seg * HH + h];

    float denp = 0.f;
    float4 acc = {0.f, 0.f, 0.f, 0.f};
    for (int p = p0; p < p1; p += 4) {
        const int pq = p + q;
        int sr_own = -1;
        float e_own = 0.f;
        if (pq < p1) {
            sr_own = esrc[pq];
            float v = lrelu(sc_src[(size_t)(g * NN + sr_own) * HH + h] + sd);
            e_own = __expf(v);
        }
        denp += e_own;
        #pragma unroll
        for (int qq = 0; qq < 4; ++qq) {
            const int srcl = (lane & ~3) | qq;
            int sr_q = __shfl(sr_own, srcl);
            float e_q = __shfl(e_own, srcl);
            if (sr_q >= 0) {
                ushort4 s4 = *(const ushort4*)(s + (size_t)(g * NN + sr_q) * DD + j * 4);
                acc.x = fmaf(e_q, bf2f(s4.x), acc.x);
                acc.y = fmaf(e_q, bf2f(s4.y), acc.y);
                acc.z = fmaf(e_q, bf2f(s4.z), acc.z);
                acc.w = fmaf(e_q, bf2f(s4.w), acc.w);
            }
        }
    }
    // den for head h = quad sum of per-lane partials
    float den = denp;
    den += __shfl_xor(den, 1);
    den += __shfl_xor(den, 2);
    float inv = (p1 > p0) ? 1.f / den : 0.f;

    float gate = 1.f / (1.f + __expf(-res_alpha[0]));
    u16x4 r4u = __builtin_nontemporal_load(
        (const u16x4*)(res_buf + (size_t)n * DD + j * 4));
    float4 og;
    og.x = fmaf(acc.x * inv, gate, bf2f(r4u[0]) * (1.f - gate));
    og.y = fmaf(acc.y * inv, gate, bf2f(r4u[1]) * (1.f - gate));
    og.z = fmaf(acc.z * inv, gate, bf2f(r4u[2]) * (1.f - gate));
    og.w = fmaf(acc.w * inv, gate, bf2f(r4u[3]) * (1.f - gate));

    float4 oo;
    oo.x = __shfl_xor(og.x, 32);
    oo.y = __shfl_xor(og.y, 32);
    oo.z = __shfl_xor(og.z, 32);
    oo.w = __shfl_xor(og.w, 32);

    float4 cw = *(const float4*)(crossW + g * DD + j * 4);
    float ds_ = og.x * cw.x + og.y * cw.y + og.z * cw.z + og.w * cw.w;
    float do_ = oo.x * cw.x + oo.y * cw.y + oo.z * cw.z + oo.w * cw.w;
    ds_ += __shfl_xor(ds_, 1); ds_ += __shfl_xor(ds_, 2);
    do_ += __shfl_xor(do_, 1); do_ += __shfl_xor(do_, 2);
    float l0 = lrelu(ds_), l1 = lrelu(do_);
    float mm = fmaxf(l0, l1);
    float e0 = __expf(l0 - mm), e1 = __expf(l1 - mm);
    float winv = 1.f / (e0 + e1);
    float w0 = e0 * winv, w1 = e1 * winv;

    f32x4 o;
    o[0] = w0 * og.x + w1 * oo.x;
    o[1] = w0 * og.y + w1 * oo.y;
    o[2] = w0 * og.z + w1 * oo.z;
    o[3] = w0 * og.w + w1 * oo.w;
    __builtin_nontemporal_store(o, (f32x4*)(out + (size_t)(g * NN + n) * DD + j * 4));
}

extern "C" void kernel_launch(void* const* d_in, const int* in_sizes, int n_in,
                              void* d_out, int out_size, void* d_ws, size_t ws_size,
                              hipStream_t stream) {
    const float* x        = (const float*)d_in[0];
    const int*   src      = (const int*)d_in[1];
    const int*   dst      = (const int*)d_in[2];
    const float* rel_emb  = (const float*)d_in[3];
    const float* Wp       = (const float*)d_in[4];
    const float* bp       = (const float*)d_in[5];
    const float* Wn       = (const float*)d_in[6];
    const float* bn       = (const float*)d_in[7];
    const float* Wsrc     = (const float*)d_in[8];
    const float* bsrc     = (const float*)d_in[9];
    const float* Wrel     = (const float*)d_in[10];
    const float* resW     = (const float*)d_in[11];
    const float* resb     = (const float*)d_in[12];
    const float* res_alpha= (const float*)d_in[13];
    const float* crossW   = (const float*)d_in[14];
    const float* Wprop    = (const float*)d_in[15];
    const float* bprop    = (const float*)d_in[16];

    float* out = (float*)d_out;

    // workspace layout: bf16 buffers first, then f32, then packed weights, ints
    ushort_t* s_bf   = (ushort_t*)d_ws;                    // R*N*D ushorts
    ushort_t* res_bf = s_bf + (size_t)RR * NN * DD;        // N*D ushorts
    float* fbase   = (float*)(res_bf + (size_t)NN * DD);
    float* sc_src  = fbase;                                // R*N*H
    float* sc_dst  = sc_src  + (size_t)RR * NN * HH;       // R*N*H
    float* avec    = sc_dst  + (size_t)RR * NN * HH;       // 512
    float* Wpn     = avec    + 512;                        // 16384
    float* Wres_c  = Wpn     + DD * DD;                    // 16384
    float* Ws_c    = Wres_c  + DD * DD;                    // 2*16384
    float* VdstT   = Ws_c    + (size_t)RR * DD * DD;       // 16*128
    float* bpn     = VdstT   + 16 * DD;                    // 128
    float* bres_c  = bpn     + DD;                         // 128
    float* bs_c    = bres_c  + DD;                         // 256
    float* cdst    = bs_c    + RR * DD;                    // 16
    float* csrc    = cdst    + 16;                         // 16
    short* Wpk     = (short*)(csrc + 16);                  // 26*4*64*8
    int*   row_ptr = (int*)(Wpk + (size_t)NT * 4 * 64 * 8);// RN + 1
    int*   binct   = row_ptr + RN + 1;                     // RR*NCH*NBIN
    int*   runoff  = binct + RR * NCH * NBIN;              // RR*NCH*NBIN
    int*   binstart= runoff + RR * NCH * NBIN;             // 520 (512 written)
    int*   bintot  = binstart + 520;                       // 512
    int*   ebuf    = bintot + 512;                         // R*E
    int*   esrc    = ebuf + RR * EE;                       // R*E

    hipMemsetAsync(bintot, 0, 512 * sizeof(int), stream);
    k_compose1<<<DD + RR * NCH, 128, 0, stream>>>(
        Wp, bp, Wn, bn, resW, resb, rel_emb, Wrel, Wprop, bprop,
        dst, binct, bintot, Wpn, bpn, Wres_c, bres_c,
        avec, out + (size_t)RR * NN * DD);
    k_compose2<<<dim3(RR, DD + 257), 128, 0, stream>>>(
        Wpn, bpn, Wsrc, bsrc, avec, binct, bintot, runoff, binstart, row_ptr,
        Ws_c, bs_c, VdstT, cdst);
    k_pack<<<NT + RR * NCH, 256, 0, stream>>>(
        Ws_c, Wres_c, VdstT, avec, bs_c, src, dst, runoff, binstart, ebuf,
        Wpk, csrc);
    k_node3<<<NB3 + RR * NBIN, 256, 0, stream>>>(
        x, Wpk, bs_c, bres_c, cdst, csrc, ebuf, binstart, row_ptr, esrc,
        s_bf, res_bf, sc_src, sc_dst);
    k_gather_cross<<<(NN + 3) / 4, 256, 0, stream>>>(esrc, row_ptr, sc_src, sc_dst,
                                                     s_bf, res_bf, res_alpha, crossW,
                                                     out);
}

// Round 18
// 191.964 us; speedup vs baseline: 1.0648x; 1.0648x over previous
//
#include <hip/hip_runtime.h>
#include <math.h>

#define NN 100000
#define EE 600000
#define RR 2
#define DD 128
#define HH 8
#define DHH 16
#define RN (RR * NN)
#define NT 26     // N-tiles: 8 (s0) + 8 (s1) + 8 (res) + 1 (sc_dst) + 1 (sc_src)
#define MTOT 6250 // total m-tiles (16 nodes each)
#define NB3 ((MTOT + 3) / 4)                  // node3 blocks (4 waves each)
#define CHUNK 4096
#define NCH ((EE + CHUNK - 1) / CHUNK)        // 147 chunks per relation
#define BINW 512
#define NBIN ((NN + BINW - 1) / BINW)         // 196 bins per relation
#define BCAPD 4096                            // LDS key capacity in binfin

typedef unsigned short ushort_t;
typedef short bf16x8 __attribute__((ext_vector_type(8)));
typedef float f32x4 __attribute__((ext_vector_type(4)));
typedef unsigned short u16x4 __attribute__((ext_vector_type(4)));

__device__ __forceinline__ float lrelu(float v) { return v >= 0.f ? v : 0.2f * v; }

// f32 -> bf16 (round to nearest even), bf16 -> f32 (exact)
__device__ __forceinline__ ushort_t f2bf(float f) {
    unsigned int u = __float_as_uint(f);
    u = (u + 0x7FFFu + ((u >> 16) & 1u)) >> 16;
    return (ushort_t)u;
}
__device__ __forceinline__ float bf2f(ushort_t u) {
    return __uint_as_float(((unsigned int)u) << 16);
}

// ---- K1: compose1 (Wpn, Wres_c, bias folds) + fused prep + trailing binct ----
// binct also atomically accumulates per-bin TOTALS into bintot (for binstart).
__global__ __launch_bounds__(128) void k_compose1(
    const float* __restrict__ Wp, const float* __restrict__ bp,
    const float* __restrict__ Wn, const float* __restrict__ bn,
    const float* __restrict__ resW, const float* __restrict__ resb,
    const float* __restrict__ rel_emb, const float* __restrict__ Wrel,
    const float* __restrict__ Wprop, const float* __restrict__ bprop,
    const int* __restrict__ dst, int* __restrict__ binct, int* __restrict__ bintot,
    float* __restrict__ Wpn, float* __restrict__ bpn,
    float* __restrict__ Wres_c, float* __restrict__ bres_c,
    float* __restrict__ avec, float* __restrict__ rel_out) {
    const int tid = threadIdx.x;
    if (blockIdx.x >= DD) {
        // ---- binct role: per-chunk coarse-bin histogram + global bin totals ----
        __shared__ int bins[NBIN];
        const int b = blockIdx.x - DD;
        const int rel = b / NCH, blk = b - rel * NCH;
        for (int i = tid; i < NBIN; i += 128) bins[i] = 0;
        __syncthreads();
        for (int i = tid; i < CHUNK; i += 128) {
            int e = blk * CHUNK + i;
            if (e < EE)
                atomicAdd(&bins[__builtin_nontemporal_load(dst + rel * EE + e) >> 9], 1);
        }
        __syncthreads();
        for (int i = tid; i < NBIN; i += 128) {
            int v = bins[i];
            binct[((rel * NCH) + blk) * NBIN + i] = v;
            if (v) atomicAdd(&bintot[rel * NBIN + i], v);
        }
        return;
    }
    __shared__ float row[DD];
    const int rrow = blockIdx.x;
    row[tid] = Wp[rrow * DD + tid];
    __syncthreads();
    float acc1 = 0.f, acc2 = 0.f;
    for (int k = 0; k < DD; ++k) {
        float wv = row[k];
        acc1 = fmaf(wv, Wn[k * DD + tid], acc1);
        acc2 = fmaf(wv, resW[k * DD + tid], acc2);
    }
    Wpn[rrow * DD + tid] = acc1;
    Wres_c[rrow * DD + tid] = acc2;
    if (rrow == 0) {
        float b1 = 0.f, b2 = 0.f;
        for (int k = 0; k < DD; ++k) {
            b1 = fmaf(bp[k], Wn[k * DD + tid], b1);
            b2 = fmaf(bp[k], resW[k * DD + tid], b2);
        }
        bpn[tid] = b1 + bn[tid];
        bres_c[tid] = b2 + resb[tid];
    }
    // fused prep
    if (rrow < 4) {
        int idx = rrow * DD + tid;          // [0,512): avec
        int r = idx >> 8, o = idx & 255;
        float acc = 0.f;
        for (int i = 0; i < 64; ++i)
            acc += rel_emb[r * 64 + i] * Wrel[(r * 64 + i) * 256 + o];
        avec[idx] = acc;
    } else if (rrow < 6) {
        int o = (rrow - 4) * DD + tid;      // [0,256): rel_out
        int r = o >> 7, oo = o & 127;
        float acc = bprop[o];
        for (int i = 0; i < 64; ++i)
            acc += rel_emb[r * 64 + i] * Wprop[(r * 64 + i) * 128 + oo];
        rel_out[o] = acc;
    }
}

// ---- K2: compose2 (Ws_c, VdstT, biases) + PARALLEL runoff scans + binstart ----
__global__ __launch_bounds__(128) void k_compose2(
    const float* __restrict__ Wpn, const float* __restrict__ bpn,
    const float* __restrict__ Wsrc, const float* __restrict__ bsrc,
    const float* __restrict__ avec,
    const int* __restrict__ binct, const int* __restrict__ bintot,
    int* __restrict__ runoff, int* __restrict__ binstart,
    int* __restrict__ row_ptr,
    float* __restrict__ Ws_c, float* __restrict__ bs_c,
    float* __restrict__ VdstT, float* __restrict__ cdst) {
    const int tid = threadIdx.x;
    if (blockIdx.y >= DD) {
        __shared__ int part[128];
        const int sidx = (blockIdx.y - DD) * RR + blockIdx.x;
        if (sidx < RR * NBIN) {
            // ---- runoff: exclusive scan of this pair's 147 chunk counts ----
            const int rel = sidx / NBIN, bin = sidx - rel * NBIN;
            int v0 = 0, v1 = 0;
            const int c0 = 2 * tid, c1 = 2 * tid + 1;
            if (c0 < NCH) v0 = binct[((rel * NCH) + c0) * NBIN + bin];
            if (c1 < NCH) v1 = binct[((rel * NCH) + c1) * NBIN + bin];
            part[tid] = v0 + v1;
            __syncthreads();
            for (int off = 1; off < 128; off <<= 1) {
                int v = (tid >= off) ? part[tid - off] : 0;
                __syncthreads();
                part[tid] += v;
                __syncthreads();
            }
            int excl = (tid == 0) ? 0 : part[tid - 1];
            if (c0 < NCH) runoff[((rel * NCH) + c0) * NBIN + bin] = excl;
            if (c1 < NCH) runoff[((rel * NCH) + c1) * NBIN + bin] = excl + v0;
        }
        if (sidx == 512) {
            // ---- exclusive scan of bintot[512] -> binstart ----
            int s[4];
            #pragma unroll
            for (int q = 0; q < 4; ++q) s[q] = bintot[4 * tid + q];
            part[tid] = s[0] + s[1] + s[2] + s[3];
            __syncthreads();
            for (int off = 1; off < 128; off <<= 1) {
                int v = (tid >= off) ? part[tid - off] : 0;
                __syncthreads();
                part[tid] += v;
                __syncthreads();
            }
            int excl = (tid == 0) ? 0 : part[tid - 1];
            binstart[4 * tid]     = excl;
            binstart[4 * tid + 1] = excl + s[0];
            binstart[4 * tid + 2] = excl + s[0] + s[1];
            binstart[4 * tid + 3] = excl + s[0] + s[1] + s[2];
            if (tid == 0) row_ptr[RN] = RR * EE;
        }
        return;
    }
    __shared__ float row[DD];
    const int rel = blockIdx.x, rrow = blockIdx.y;
    row[tid] = Wpn[rrow * DD + tid];
    __syncthreads();
    const float* W = Wsrc + (size_t)rel * DD * DD;
    float acc = 0.f;
    for (int k = 0; k < DD; ++k) acc = fmaf(row[k], W[k * DD + tid], acc);
    Ws_c[(size_t)rel * DD * DD + rrow * DD + tid] = acc;
    if (tid < HH) {  // head = tid
        float v = 0.f;
        for (int d = 0; d < 16; ++d)
            v += row[tid * 16 + d] * avec[rel * 256 + tid * 32 + 16 + d];
        VdstT[(rel * HH + tid) * DD + rrow] = v;
    }
    if (rrow == 0) {
        float b = 0.f;
        for (int k = 0; k < DD; ++k) b = fmaf(bpn[k], W[k * DD + tid], b);
        bs_c[rel * DD + tid] = b + bsrc[rel * DD + tid];
        if (rel == 0 && tid < 16) {
            int r2 = tid >> 3, h2 = tid & 7;
            float c2 = 0.f;
            for (int d = 0; d < 16; ++d)
                c2 += bpn[h2 * 16 + d] * avec[r2 * 256 + h2 * 32 + 16 + d];
            cdst[tid] = c2;
        }
    }
}

// ---- K3: pack (MFMA B-fragments) + trailing binfill ----
__global__ __launch_bounds__(256) void k_pack(
    const float* __restrict__ Ws_c, const float* __restrict__ Wres_c,
    const float* __restrict__ VdstT, const float* __restrict__ avec,
    const float* __restrict__ bs_c,
    const int* __restrict__ src, const int* __restrict__ dst,
    const int* __restrict__ runoff, const int* __restrict__ binstart,
    int* __restrict__ ebuf,
    short* __restrict__ Wpk, float* __restrict__ csrc) {
    const int tid = threadIdx.x;
    if (blockIdx.x >= NT) {
        // ---- binfill role ----
        __shared__ int ofs[NBIN];
        __shared__ int bins[NBIN];
        const int b = blockIdx.x - NT;
        const int rel = b / NCH, blk = b - rel * NCH;
        if (tid < NBIN) {
            ofs[tid] = binstart[rel * NBIN + tid] +
                       runoff[((rel * NCH) + blk) * NBIN + tid];
            bins[tid] = 0;
        }
        __syncthreads();
        for (int i = tid; i < CHUNK; i += 256) {
            int e = blk * CHUNK + i;
            if (e < EE) {
                int d = __builtin_nontemporal_load(dst + rel * EE + e);
                int bb = d >> 9;
                int loc = atomicAdd(&bins[bb], 1);
                ebuf[ofs[bb] + loc] =
                    ((d & 511) << 17) | __builtin_nontemporal_load(src + rel * EE + e);
            }
        }
        return;
    }
    const int t = blockIdx.x;
    const int kt = tid >> 6;
    const int l = tid & 63;
    const int c16 = l & 15;
    bf16x8 v;
    #pragma unroll
    for (int j = 0; j < 8; ++j) {
        int k = kt * 32 + (l >> 4) * 8 + j;
        float f;
        if (t < 24) {
            int m = t >> 3;                    // 0=Ws0, 1=Ws1, 2=Wres
            int col = (t & 7) * 16 + c16;
            const float* W = (m == 0) ? Ws_c : (m == 1) ? Ws_c + DD * DD : Wres_c;
            f = W[k * DD + col];
        } else if (t == 24) {
            f = VdstT[c16 * DD + k];
        } else {
            int rel = c16 >> 3, h = c16 & 7;
            f = 0.f;
            for (int d = 0; d < 16; ++d)
                f += Ws_c[(size_t)rel * DD * DD + k * DD + h * 16 + d]
                     * avec[rel * 256 + h * 32 + d];
        }
        v[j] = (short)f2bf(f);
    }
    *(bf16x8*)(Wpk + ((size_t)(t * 4 + kt) * 64 + l) * 8) = v;
    if (t == 25 && tid < 16) {
        int rel = tid >> 3, h = tid & 7;
        float c = 0.f;
        for (int d = 0; d < 16; ++d)
            c += bs_c[rel * DD + h * 16 + d] * avec[rel * 256 + h * 32 + d];
        csrc[tid] = c;
    }
}

// ---- K4: node GEMM via MFMA + trailing binfin ----
__global__ __launch_bounds__(256) void k_node3(
    const float* __restrict__ x, const short* __restrict__ Wpk,
    const float* __restrict__ bs_c, const float* __restrict__ bres_c,
    const float* __restrict__ cdst, const float* __restrict__ csrc,
    const int* __restrict__ ebuf, const int* __restrict__ binstart,
    int* __restrict__ row_ptr, int* __restrict__ esrc,
    ushort_t* __restrict__ s_out, ushort_t* __restrict__ res_out,
    float* __restrict__ sc_src, float* __restrict__ sc_dst) {
    const int tid = threadIdx.x;
    if (blockIdx.x >= NB3) {
        // ---- binfin role: per-node counts + LDS scan -> row_ptr + esrc ----
        __shared__ int keys[BCAPD];
        __shared__ int cnt[BINW];
        __shared__ int scn[BINW];
        __shared__ int part[256];
        const int b = blockIdx.x - NB3;
        const int rel = b / NBIN, bin = b - rel * NBIN;
        const int p0 = binstart[rel * NBIN + bin];
        const int p1 = binstart[rel * NBIN + bin + 1];
        const int cntE = p1 - p0;
        const bool inlds = (cntE <= BCAPD);
        const int n0 = bin * BINW;
        const int nw = min(BINW, NN - n0);

        cnt[2 * tid] = 0; cnt[2 * tid + 1] = 0;
        __syncthreads();
        for (int i = tid; i < cntE; i += 256) {
            int k = __builtin_nontemporal_load(ebuf + p0 + i);
            if (inlds) keys[i] = k;
            atomicAdd(&cnt[k >> 17], 1);
        }
        __syncthreads();
        int a = cnt[2 * tid], c = cnt[2 * tid + 1];
        part[tid] = a + c;
        __syncthreads();
        for (int off = 1; off < 256; off <<= 1) {
            int v = (tid >= off) ? part[tid - off] : 0;
            __syncthreads();
            part[tid] += v;
            __syncthreads();
        }
        int excl = (tid == 0) ? 0 : part[tid - 1];
        scn[2 * tid] = excl;
        scn[2 * tid + 1] = excl + a;
        cnt[2 * tid] = 0; cnt[2 * tid + 1] = 0;   // reuse as placement cursors
        __syncthreads();
        for (int n = tid; n < nw; n += 256)
            row_ptr[rel * NN + n0 + n] = p0 + scn[n];
        for (int i = tid; i < cntE; i += 256) {
            int k = inlds ? keys[i] : ebuf[p0 + i];
            int low = k >> 17;
            int slot = atomicAdd(&cnt[low], 1);
            esrc[p0 + scn[low] + slot] = k & 0x1FFFF;
        }
        return;
    }
    const int l = tid & 63;
    const int w = tid >> 6;
    const int m16 = l & 15, g4 = l >> 4;
    const int mt = blockIdx.x * 4 + w;
    const bool live = (mt < MTOT);
    const int nb = (live ? mt : MTOT - 1) * 16;

    bf16x8 af[4];
    const float* xrow = x + (size_t)(nb + m16) * DD + g4 * 8;
    #pragma unroll
    for (int kt = 0; kt < 4; ++kt) {
        float4 v0 = *(const float4*)(xrow + kt * 32);
        float4 v1 = *(const float4*)(xrow + kt * 32 + 4);
        af[kt][0] = (short)f2bf(v0.x); af[kt][1] = (short)f2bf(v0.y);
        af[kt][2] = (short)f2bf(v0.z); af[kt][3] = (short)f2bf(v0.w);
        af[kt][4] = (short)f2bf(v1.x); af[kt][5] = (short)f2bf(v1.y);
        af[kt][6] = (short)f2bf(v1.z); af[kt][7] = (short)f2bf(v1.w);
    }

    for (int t = 0; t < NT; ++t) {
        f32x4 acc = {0.f, 0.f, 0.f, 0.f};
        #pragma unroll
        for (int kt = 0; kt < 4; ++kt) {
            bf16x8 b = *(const bf16x8*)(Wpk + ((size_t)(t * 4 + kt) * 64 + l) * 8);
            acc = __builtin_amdgcn_mfma_f32_16x16x32_bf16(af[kt], b, acc, 0, 0, 0);
        }
        if (!live) continue;
        if (t < 16) {
            const int rel = t >> 3, head = t & 7;
            const float bb = bs_c[rel * DD + head * 16 + m16];
            #pragma unroll
            for (int r = 0; r < 4; ++r) {
                const int node = nb + g4 * 4 + r;
                s_out[((size_t)rel * NN + node) * DD + head * 16 + m16] =
                    f2bf(acc[r] + bb);
            }
        } else if (t < 24) {
            const int col = (t - 16) * 16 + m16;
            const float bb = bres_c[col];
            #pragma unroll
            for (int r = 0; r < 4; ++r) {
                const int node = nb + g4 * 4 + r;
                res_out[(size_t)node * DD + col] = f2bf(acc[r] + bb);
            }
        } else if (t == 24) {
            const int rel = m16 >> 3, head = m16 & 7;
            const float bb = cdst[m16];
            #pragma unroll
            for (int r = 0; r < 4; ++r) {
                const int node = nb + g4 * 4 + r;
                sc_dst[((size_t)rel * NN + node) * HH + head] = acc[r] + bb;
            }
        } else {
            const int rel = m16 >> 3, head = m16 & 7;
            const float bb = csrc[m16];
            #pragma unroll
            for (int r = 0; r < 4; ++r) {
                const int node = nb + g4 * 4 + r;
                sc_src[((size_t)rel * NN + node) * HH + head] = acc[r] + bb;
            }
        }
    }
}

// ---- K5: fused gather: single-pass softmax + agg + gate + cross ----
__global__ __launch_bounds__(256) void k_gather_cross(
    const int* __restrict__ esrc, const int* __restrict__ row_ptr,
    const float* __restrict__ sc_src, const float* __restrict__ sc_dst,
    const ushort_t* __restrict__ s, const ushort_t* __restrict__ res_buf,
    const float* __restrict__ res_alpha, const float* __restrict__ crossW,
    float* __restrict__ out) {
    int n = blockIdx.x * 4 + (threadIdx.x >> 6);
    if (n >= NN) return;
    const int lane = threadIdx.x & 63;
    const int g = lane >> 5;
    const int j = lane & 31;
    const int h = j >> 2;

    const int seg = g * NN + n;
    const int p0 = row_ptr[seg], p1 = row_ptr[seg + 1];
    const float sd = sc_dst[(size_t)seg * HH + h];

    float den0 = 0.f, den1 = 0.f;
    float4 acc0 = {0.f, 0.f, 0.f, 0.f}, acc1 = {0.f, 0.f, 0.f, 0.f};
    int p = p0;
    for (; p + 1 < p1; p += 2) {
        int sr0 = esrc[p], sr1 = esrc[p + 1];
        ushort4 s40 = *(const ushort4*)(s + (size_t)(g * NN + sr0) * DD + j * 4);
        ushort4 s41 = *(const ushort4*)(s + (size_t)(g * NN + sr1) * DD + j * 4);
        float v0 = lrelu(sc_src[(size_t)(g * NN + sr0) * HH + h] + sd);
        float v1 = lrelu(sc_src[(size_t)(g * NN + sr1) * HH + h] + sd);
        float e0 = __expf(v0);
        float e1 = __expf(v1);
        den0 += e0; den1 += e1;
        acc0.x = fmaf(e0, bf2f(s40.x), acc0.x); acc1.x = fmaf(e1, bf2f(s41.x), acc1.x);
        acc0.y = fmaf(e0, bf2f(s40.y), acc0.y); acc1.y = fmaf(e1, bf2f(s41.y), acc1.y);
        acc0.z = fmaf(e0, bf2f(s40.z), acc0.z); acc1.z = fmaf(e1, bf2f(s41.z), acc1.z);
        acc0.w = fmaf(e0, bf2f(s40.w), acc0.w); acc1.w = fmaf(e1, bf2f(s41.w), acc1.w);
    }
    if (p < p1) {
        int sr0 = esrc[p];
        ushort4 s40 = *(const ushort4*)(s + (size_t)(g * NN + sr0) * DD + j * 4);
        float v0 = lrelu(sc_src[(size_t)(g * NN + sr0) * HH + h] + sd);
        float e0 = __expf(v0);
        den0 += e0;
        acc0.x = fmaf(e0, bf2f(s40.x), acc0.x);
        acc0.y = fmaf(e0, bf2f(s40.y), acc0.y);
        acc0.z = fmaf(e0, bf2f(s40.z), acc0.z);
        acc0.w = fmaf(e0, bf2f(s40.w), acc0.w);
    }
    float den = den0 + den1;
    float4 acc = {acc0.x + acc1.x, acc0.y + acc1.y, acc0.z + acc1.z, acc0.w + acc1.w};
    float inv = (p1 > p0) ? 1.f / den : 0.f;

    float gate = 1.f / (1.f + __expf(-res_alpha[0]));
    u16x4 r4u = __builtin_nontemporal_load(
        (const u16x4*)(res_buf + (size_t)n * DD + j * 4));
    float4 og;
    og.x = fmaf(acc.x * inv, gate, bf2f(r4u[0]) * (1.f - gate));
    og.y = fmaf(acc.y * inv, gate, bf2f(r4u[1]) * (1.f - gate));
    og.z = fmaf(acc.z * inv, gate, bf2f(r4u[2]) * (1.f - gate));
    og.w = fmaf(acc.w * inv, gate, bf2f(r4u[3]) * (1.f - gate));

    float4 oo;
    oo.x = __shfl_xor(og.x, 32);
    oo.y = __shfl_xor(og.y, 32);
    oo.z = __shfl_xor(og.z, 32);
    oo.w = __shfl_xor(og.w, 32);

    float4 cw = *(const float4*)(crossW + g * DD + j * 4);
    float ds_ = og.x * cw.x + og.y * cw.y + og.z * cw.z + og.w * cw.w;
    float do_ = oo.x * cw.x + oo.y * cw.y + oo.z * cw.z + oo.w * cw.w;
    ds_ += __shfl_xor(ds_, 1); ds_ += __shfl_xor(ds_, 2);
    do_ += __shfl_xor(do_, 1); do_ += __shfl_xor(do_, 2);
    float l0 = lrelu(ds_), l1 = lrelu(do_);
    float mm = fmaxf(l0, l1);
    float e0 = __expf(l0 - mm), e1 = __expf(l1 - mm);
    float winv = 1.f / (e0 + e1);
    float w0 = e0 * winv, w1 = e1 * winv;

    f32x4 o;
    o[0] = w0 * og.x + w1 * oo.x;
    o[1] = w0 * og.y + w1 * oo.y;
    o[2] = w0 * og.z + w1 * oo.z;
    o[3] = w0 * og.w + w1 * oo.w;
    __builtin_nontemporal_store(o, (f32x4*)(out + (size_t)(g * NN + n) * DD + j * 4));
}

extern "C" void kernel_launch(void* const* d_in, const int* in_sizes, int n_in,
                              void* d_out, int out_size, void* d_ws, size_t ws_size,
                              hipStream_t stream) {
    const float* x        = (const float*)d_in[0];
    const int*   src      = (const int*)d_in[1];
    const int*   dst      = (const int*)d_in[2];
    const float* rel_emb  = (const float*)d_in[3];
    const float* Wp       = (const float*)d_in[4];
    const float* bp       = (const float*)d_in[5];
    const float* Wn       = (const float*)d_in[6];
    const float* bn       = (const float*)d_in[7];
    const float* Wsrc     = (const float*)d_in[8];
    const float* bsrc     = (const float*)d_in[9];
    const float* Wrel     = (const float*)d_in[10];
    const float* resW     = (const float*)d_in[11];
    const float* resb     = (const float*)d_in[12];
    const float* res_alpha= (const float*)d_in[13];
    const float* crossW   = (const float*)d_in[14];
    const float* Wprop    = (const float*)d_in[15];
    const float* bprop    = (const float*)d_in[16];

    float* out = (float*)d_out;

    // workspace layout: bf16 buffers first, then f32, then packed weights, ints
    ushort_t* s_bf   = (ushort_t*)d_ws;                    // R*N*D ushorts
    ushort_t* res_bf = s_bf + (size_t)RR * NN * DD;        // N*D ushorts
    float* fbase   = (float*)(res_bf + (size_t)NN * DD);
    float* sc_src  = fbase;                                // R*N*H
    float* sc_dst  = sc_src  + (size_t)RR * NN * HH;       // R*N*H
    float* avec    = sc_dst  + (size_t)RR * NN * HH;       // 512
    float* Wpn     = avec    + 512;                        // 16384
    float* Wres_c  = Wpn     + DD * DD;                    // 16384
    float* Ws_c    = Wres_c  + DD * DD;                    // 2*16384
    float* VdstT   = Ws_c    + (size_t)RR * DD * DD;       // 16*128
    float* bpn     = VdstT   + 16 * DD;                    // 128
    float* bres_c  = bpn     + DD;                         // 128
    float* bs_c    = bres_c  + DD;                         // 256
    float* cdst    = bs_c    + RR * DD;                    // 16
    float* csrc    = cdst    + 16;                         // 16
    short* Wpk     = (short*)(csrc + 16);                  // 26*4*64*8
    int*   row_ptr = (int*)(Wpk + (size_t)NT * 4 * 64 * 8);// RN + 1
    int*   binct   = row_ptr + RN + 1;                     // RR*NCH*NBIN
    int*   runoff  = binct + RR * NCH * NBIN;              // RR*NCH*NBIN
    int*   binstart= runoff + RR * NCH * NBIN;             // 520 (512 written)
    int*   bintot  = binstart + 520;                       // 512
    int*   ebuf    = bintot + 512;                         // R*E
    int*   esrc    = ebuf + RR * EE;                       // R*E

    hipMemsetAsync(bintot, 0, 512 * sizeof(int), stream);
    k_compose1<<<DD + RR * NCH, 128, 0, stream>>>(
        Wp, bp, Wn, bn, resW, resb, rel_emb, Wrel, Wprop, bprop,
        dst, binct, bintot, Wpn, bpn, Wres_c, bres_c,
        avec, out + (size_t)RR * NN * DD);
    k_compose2<<<dim3(RR, DD + 257), 128, 0, stream>>>(
        Wpn, bpn, Wsrc, bsrc, avec, binct, bintot, runoff, binstart, row_ptr,
        Ws_c, bs_c, VdstT, cdst);
    k_pack<<<NT + RR * NCH, 256, 0, stream>>>(
        Ws_c, Wres_c, VdstT, avec, bs_c, src, dst, runoff, binstart, ebuf,
        Wpk, csrc);
    k_node3<<<NB3 + RR * NBIN, 256, 0, stream>>>(
        x, Wpk, bs_c, bres_c, cdst, csrc, ebuf, binstart, row_ptr, esrc,
        s_bf, res_bf, sc_src, sc_dst);
    k_gather_cross<<<(NN + 3) / 4, 256, 0, stream>>>(esrc, row_ptr, sc_src, sc_dst,
                                                     s_bf, res_bf, res_alpha, crossW,
                                                     out);
}